// Round 1
// 662.000 us; speedup vs baseline: 1.0114x; 1.0114x over previous
//
#include <hip/hip_runtime.h>
#include <math.h>

// Problem constants (DeepseekV2 MLA decode)
constexpr int kH    = 5120;
constexpr int kQLR  = 1536;
constexpr int kNH   = 128;
constexpr int kDQ   = 192;
constexpr int kDN   = 128;
constexpr int kDR   = 64;
constexpr int kKVLR = 512;
constexpr int kDV   = 128;

// ---------------------------------------------------------------------------
// 2-batch GEMV, 2 rows per wave, split-K over blockIdx.y.
// y[b,row] = sum_i W[row,i]*x[b,i].  ATOMIC=true -> atomicAdd partials.
// grid (R/8, SPLIT), block 256.
// ---------------------------------------------------------------------------
template<int IN, int SPLIT, bool ATOMIC>
__global__ __launch_bounds__(256) void gemv2_k(const float* __restrict__ W,
                                               const float* __restrict__ x,
                                               float* __restrict__ y, int R) {
  constexpr int CH = IN / SPLIT;
  constexpr int F4 = CH / 256;  // float4 per lane per row-chunk
  int lane = threadIdx.x & 63, wave = threadIdx.x >> 6;
  int r0 = blockIdx.x * 8 + wave * 2;
  int c0 = blockIdx.y * CH;
  const float4* W0 = (const float4*)(W + (size_t)r0 * IN + c0);
  const float4* W1 = (const float4*)(W + (size_t)(r0 + 1) * IN + c0);
  const float4* x0 = (const float4*)(x + c0);
  const float4* x1 = (const float4*)(x + IN + c0);
  float a00 = 0.f, a01 = 0.f, a10 = 0.f, a11 = 0.f;
#pragma unroll 4
  for (int i = 0; i < F4; ++i) {
    int idx = lane + (i << 6);
    float4 w0 = W0[idx];
    float4 w1 = W1[idx];
    float4 u = x0[idx];
    float4 v = x1[idx];
    a00 = fmaf(w0.x,u.x,fmaf(w0.y,u.y,fmaf(w0.z,u.z,fmaf(w0.w,u.w,a00))));
    a01 = fmaf(w0.x,v.x,fmaf(w0.y,v.y,fmaf(w0.z,v.z,fmaf(w0.w,v.w,a01))));
    a10 = fmaf(w1.x,u.x,fmaf(w1.y,u.y,fmaf(w1.z,u.z,fmaf(w1.w,u.w,a10))));
    a11 = fmaf(w1.x,v.x,fmaf(w1.y,v.y,fmaf(w1.z,v.z,fmaf(w1.w,v.w,a11))));
  }
#pragma unroll
  for (int off = 32; off > 0; off >>= 1) {
    a00 += __shfl_down(a00, off, 64);
    a01 += __shfl_down(a01, off, 64);
    a10 += __shfl_down(a10, off, 64);
    a11 += __shfl_down(a11, off, 64);
  }
  if (lane == 0) {
    if (ATOMIC) {
      atomicAdd(&y[r0], a00);
      atomicAdd(&y[(size_t)R + r0], a01);
      atomicAdd(&y[r0 + 1], a10);
      atomicAdd(&y[(size_t)R + r0 + 1], a11);
    } else {
      y[r0] = a00;
      y[(size_t)R + r0] = a01;
      y[r0 + 1] = a10;
      y[(size_t)R + r0 + 1] = a11;
    }
  }
}

// ---------------------------------------------------------------------------
// RMSNorm over QLR=1536 per batch
// ---------------------------------------------------------------------------
__global__ __launch_bounds__(256) void rmsnorm_k(const float* __restrict__ qa,
                                                 const float* __restrict__ w,
                                                 float* __restrict__ out) {
  int b = blockIdx.x, t = threadIdx.x;
  const float* x = qa + (size_t)b * kQLR;
  float s = 0.f;
  for (int i = t; i < kQLR; i += 256) { float v = x[i]; s = fmaf(v, v, s); }
  __shared__ float red[4];
#pragma unroll
  for (int off = 32; off > 0; off >>= 1) s += __shfl_down(s, off, 64);
  if ((t & 63) == 0) red[t >> 6] = s;
  __syncthreads();
  float tot = red[0] + red[1] + red[2] + red[3];
  float scale = rsqrtf(tot / (float)kQLR + 1e-6f);
  for (int i = t; i < kQLR; i += 256) out[(size_t)b * kQLR + i] = x[i] * scale * w[i];
}

// ---------------------------------------------------------------------------
// q absorption, d-split with atomics:
// qabs[b,h,c] += sum_{d in split} q_nope[b,h,d] * kv_b_w[h*256+d, c]
// grid (NH, 4), block 256 (thread -> float2 column).
// ---------------------------------------------------------------------------
__global__ __launch_bounds__(256) void qabs_k(const float* __restrict__ q,
                                              const float* __restrict__ kvw,
                                              float* __restrict__ qabs) {
  int h = blockIdx.x, ds = blockIdx.y;
  int t = threadIdx.x;
  __shared__ float qn[2][32];
  if (t < 64) {
    int b = t >> 5, d = t & 31;
    qn[b][d] = q[((size_t)b * kNH + h) * kDQ + ds * 32 + d];
  }
  __syncthreads();
  float a0x = 0.f, a0y = 0.f, a1x = 0.f, a1y = 0.f;
  const float* wb = kvw + ((size_t)h * 256 + ds * 32) * kKVLR + t * 2;
#pragma unroll 4
  for (int d = 0; d < 32; ++d) {
    float2 w = *(const float2*)(wb + (size_t)d * kKVLR);
    float q0 = qn[0][d], q1 = qn[1][d];
    a0x = fmaf(q0, w.x, a0x); a0y = fmaf(q0, w.y, a0y);
    a1x = fmaf(q1, w.x, a1x); a1y = fmaf(q1, w.y, a1y);
  }
  float* p0 = qabs + (size_t)h * kKVLR + t * 2;
  float* p1 = qabs + ((size_t)kNH + h) * kKVLR + t * 2;
  atomicAdd(p0, a0x); atomicAdd(p0 + 1, a0y);
  atomicAdd(p1, a1x); atomicAdd(p1 + 1, a1y);
}

// ---------------------------------------------------------------------------
// Fused flash attention over a 64-kv split:
//   - rope(k_pe) fused into LDS staging; rope(q_pe) into LDS tile
//   - scores = (qabs.c + q_pe_rot.k_pe_rot)/sqrt(192)
//   - per-split softmax partial: m=max, p=exp(s-m), l=sum(p)
//   - ctx partial: ctxp[ks,b,h,:] = sum_k p*c   (unnormalized)
//   - (m,l) stored to ml for the weighted fold in vproj_k
// grid (KV/64, 8 head-groups-of-16, B), block 256; wave handles 4 heads in QK.
// LDS ~59 KB -> 2 blocks/CU; grid 512 = fully resident.
// ---------------------------------------------------------------------------
__global__ __launch_bounds__(256) void attn_k(const float* __restrict__ qabs,
                                              const float* __restrict__ qfull,
                                              const float* __restrict__ c,
                                              const float* __restrict__ kpe,
                                              float* __restrict__ ctxp,
                                              float* __restrict__ ml, int KV) {
  int ks = blockIdx.x, hg = blockIdx.y, b = blockIdx.z;
  int t = threadIdx.x, lane = t & 63, wave = t >> 6;
  int h0 = __builtin_amdgcn_readfirstlane(hg * 16 + wave * 4);
  int k0 = ks * 64;
  __shared__ float cl[64 * 129];   // c chunk [64][128] (+1 pad)
  __shared__ float kl[64 * 65];    // rotated k_pe [64][64] (+1 pad)
  __shared__ float ql[16 * 64];    // rotated q_pe for 16 heads
  __shared__ float al[64 * 20];    // p values [k][head-in-group]

  constexpr float kNegLog = -0.28782313662425572f;  // -ln(10000)/32

  // stage + rotate k_pe chunk [64][64]
  {
    const float4* src = (const float4*)(kpe + ((size_t)b * KV + k0) * kDR);
#pragma unroll
    for (int i = 0; i < 4; ++i) {
      int idx = t + i * 256;
      int r = idx >> 4, c4 = idx & 15;
      float4 v = src[r * 16 + c4];
      float fk = (float)(k0 + r);
      float inv0 = expf(kNegLog * (float)(c4 * 2));
      float inv1 = expf(kNegLog * (float)(c4 * 2 + 1));
      float s0, c0, s1, c1;
      sincosf(fk * inv0, &s0, &c0);
      sincosf(fk * inv1, &s1, &c1);
      float* d = &kl[r * 65 + (c4 << 2)];
      d[0] = v.x * c0 - v.y * s0;
      d[1] = v.x * s0 + v.y * c0;
      d[2] = v.z * c1 - v.w * s1;
      d[3] = v.z * s1 + v.w * c1;
    }
  }
  // rotate q_pe for this head group into ql (pos = KV-1)
  {
    float fp = (float)(KV - 1);
    for (int pi = t; pi < 512; pi += 256) {
      int j = pi >> 5, i = pi & 31;
      float inv = expf(kNegLog * (float)i);
      float s, cc;
      sincosf(fp * inv, &s, &cc);
      const float* qp = qfull + ((size_t)b * kNH + hg * 16 + j) * kDQ + kDN + 2 * i;
      float x0 = qp[0], x1 = qp[1];
      ql[j * 64 + 2 * i]     = x0 * cc - x1 * s;
      ql[j * 64 + 2 * i + 1] = x0 * s + x1 * cc;
    }
  }

  float acc[4] = {0.f, 0.f, 0.f, 0.f};
  for (int cch = 0; cch < 4; ++cch) {
    __syncthreads();
    const float* cb = c + ((size_t)b * KV + k0) * kKVLR + cch * 128;
#pragma unroll
    for (int i = 0; i < 8; ++i) {
      int idx = t + i * 256;
      int r = idx >> 5, c4 = idx & 31;
      float4 v = *(const float4*)(cb + (size_t)r * kKVLR + (c4 << 2));
      float* d = &cl[r * 129 + (c4 << 2)];
      d[0] = v.x; d[1] = v.y; d[2] = v.z; d[3] = v.w;
    }
    __syncthreads();
    const float* qb = qabs + ((size_t)b * kNH + h0) * kKVLR + cch * 128;
#pragma unroll 4
    for (int cc2 = 0; cc2 < 128; ++cc2) {
      float cv = cl[lane * 129 + cc2];
#pragma unroll
      for (int j = 0; j < 4; ++j)
        acc[j] = fmaf(cv, qb[(size_t)j * kKVLR + cc2], acc[j]);
    }
  }
  // pe contribution (kl rows x ql broadcast)
  {
#pragma unroll 4
    for (int i = 0; i < 64; ++i) {
      float kv = kl[lane * 65 + i];
#pragma unroll
      for (int j = 0; j < 4; ++j)
        acc[j] = fmaf(kv, ql[(wave * 4 + j) * 64 + i], acc[j]);
    }
  }

  // per-head softmax partial over this split's 64 kv (cross-lane)
  const float scale = 1.0f / sqrtf(192.0f);
  float pj[4], mj[4], lj[4];
#pragma unroll
  for (int j = 0; j < 4; ++j) {
    float s = acc[j] * scale;
    float m = s;
#pragma unroll
    for (int off = 32; off > 0; off >>= 1) m = fmaxf(m, __shfl_xor(m, off, 64));
    float p = __expf(s - m);
    float l = p;
#pragma unroll
    for (int off = 32; off > 0; off >>= 1) l += __shfl_xor(l, off, 64);
    pj[j] = p; mj[j] = m; lj[j] = l;
  }
  *(float4*)&al[lane * 20 + wave * 4] = make_float4(pj[0], pj[1], pj[2], pj[3]);
  if (lane == 0) {
#pragma unroll
    for (int j = 0; j < 4; ++j) {
      float2* mp = (float2*)(ml + (((size_t)b * kNH + h0 + j) * 32 + ks) * 2);
      *mp = make_float2(mj[j], lj[j]);
    }
  }
  __syncthreads();

  // PV partial (unnormalized): thread -> float2 column of 512
  float2 accv[16];
#pragma unroll
  for (int j = 0; j < 16; ++j) accv[j] = make_float2(0.f, 0.f);
  const float2* c2 = (const float2*)(c + ((size_t)b * KV + k0) * kKVLR);
#pragma unroll 2
  for (int k = 0; k < 64; ++k) {
    float2 cv = c2[k * (kKVLR / 2) + t];
#pragma unroll
    for (int j4 = 0; j4 < 4; ++j4) {
      float4 av = *(const float4*)&al[k * 20 + j4 * 4];
      accv[j4*4+0].x = fmaf(av.x, cv.x, accv[j4*4+0].x);
      accv[j4*4+0].y = fmaf(av.x, cv.y, accv[j4*4+0].y);
      accv[j4*4+1].x = fmaf(av.y, cv.x, accv[j4*4+1].x);
      accv[j4*4+1].y = fmaf(av.y, cv.y, accv[j4*4+1].y);
      accv[j4*4+2].x = fmaf(av.z, cv.x, accv[j4*4+2].x);
      accv[j4*4+2].y = fmaf(av.z, cv.y, accv[j4*4+2].y);
      accv[j4*4+3].x = fmaf(av.w, cv.x, accv[j4*4+3].x);
      accv[j4*4+3].y = fmaf(av.w, cv.y, accv[j4*4+3].y);
    }
  }
#pragma unroll
  for (int j = 0; j < 16; ++j) {
    float2* dst = (float2*)(ctxp + (((size_t)ks * 2 + b) * kNH + hg * 16 + j) * kKVLR);
    dst[t] = accv[j];
  }
}

// ---------------------------------------------------------------------------
// weighted fold of 32 flash partials + v-projection:
//   M = max_s m_s ; w_s = exp(m_s - M) ; L = sum w_s*l_s
//   ctx = (sum_s w_s * ctxp_s) ; oh = (W_v . ctx) / L
// grid (NH, 4 d-quarters), block 256.
// ---------------------------------------------------------------------------
__global__ __launch_bounds__(256) void vproj_k(const float* __restrict__ ctxp,
                                               const float* __restrict__ ml,
                                               const float* __restrict__ kvw,
                                               float* __restrict__ oh) {
  int h = blockIdx.x, dq = blockIdx.y;
  int t = threadIdx.x, lane = t & 63, wave = t >> 6;
  __shared__ float cf[2 * kKVLR];
  __shared__ float invl[2];
  {
    int b = t >> 7, g = t & 127;
    const float2* mlb = (const float2*)(ml + ((size_t)b * kNH + h) * 64);
    float M = -1e30f;
#pragma unroll 8
    for (int s = 0; s < 32; ++s) M = fmaxf(M, mlb[s].x);
    float L = 0.f;
    float4 a4 = make_float4(0.f, 0.f, 0.f, 0.f);
#pragma unroll 4
    for (int s = 0; s < 32; ++s) {
      float2 e = mlb[s];
      float w = __expf(e.x - M);
      L = fmaf(w, e.y, L);
      const float4* p = (const float4*)(ctxp + (((size_t)s * 2 + b) * kNH + h) * kKVLR);
      float4 v = p[g];
      a4.x = fmaf(w, v.x, a4.x);
      a4.y = fmaf(w, v.y, a4.y);
      a4.z = fmaf(w, v.z, a4.z);
      a4.w = fmaf(w, v.w, a4.w);
    }
    *(float4*)&cf[b * kKVLR + (g << 2)] = a4;
    if (g == 0) invl[b] = 1.0f / L;
  }
  __syncthreads();
  float cr0[8], cr1[8];
#pragma unroll
  for (int j = 0; j < 8; ++j) {
    cr0[j] = cf[lane * 8 + j];
    cr1[j] = cf[kKVLR + lane * 8 + j];
  }
#pragma unroll
  for (int i = 0; i < 8; ++i) {
    int d = dq * 32 + wave * 8 + i;
    const float4* w4 = (const float4*)(kvw + ((size_t)h * 256 + 128 + d) * kKVLR) + lane * 2;
    float4 wa = w4[0], wb = w4[1];
    float s0 = wa.x * cr0[0] + wa.y * cr0[1] + wa.z * cr0[2] + wa.w * cr0[3]
             + wb.x * cr0[4] + wb.y * cr0[5] + wb.z * cr0[6] + wb.w * cr0[7];
    float s1 = wa.x * cr1[0] + wa.y * cr1[1] + wa.z * cr1[2] + wa.w * cr1[3]
             + wb.x * cr1[4] + wb.y * cr1[5] + wb.z * cr1[6] + wb.w * cr1[7];
#pragma unroll
    for (int off = 32; off > 0; off >>= 1) {
      s0 += __shfl_down(s0, off, 64);
      s1 += __shfl_down(s1, off, 64);
    }
    if (lane == 0) {
      oh[(size_t)h * kDV + d] = s0 * invl[0];
      oh[((size_t)kNH + h) * kDV + d] = s1 * invl[1];
    }
  }
}

// ---------------------------------------------------------------------------
extern "C" void kernel_launch(void* const* d_in, const int* in_sizes, int n_in,
                              void* d_out, int out_size, void* d_ws, size_t ws_size,
                              hipStream_t stream) {
  const float* hs   = (const float*)d_in[0];
  const float* ckv  = (const float*)d_in[1];
  const float* kpe  = (const float*)d_in[2];
  const float* qaw  = (const float*)d_in[3];
  const float* qlnw = (const float*)d_in[4];
  const float* qbw  = (const float*)d_in[5];
  const float* kvbw = (const float*)d_in[6];
  const float* ow   = (const float*)d_in[7];
  float* out = (float*)d_out;

  int B  = in_sizes[0] / kH;              // 2
  int KV = in_sizes[2] / (B * kDR);       // 2048

  float* ws   = (float*)d_ws;
  // layout: [qa | qabs] contiguous (single memset), then the rest
  float* qa   = ws;                                    // B*QLR
  float* qabs = qa + (size_t)B * kQLR;                 // B*NH*KVLR
  float* qan  = qabs + (size_t)B * kNH * kKVLR;        // B*QLR
  float* q    = qan + (size_t)B * kQLR;                // B*NH*DQ
  float* ctxp = q + (size_t)B * kNH * kDQ;             // 32*B*NH*KVLR
  float* ml   = ctxp + (size_t)32 * B * kNH * kKVLR;   // B*NH*32*2 (m,l)
  float* oh   = ml + (size_t)B * kNH * 64;             // B*NH*DV

  // zero atomic-accumulation targets (qa+qabs contiguous -> one memset)
  hipMemsetAsync(qa, 0, ((size_t)B * kQLR + (size_t)B * kNH * kKVLR) * sizeof(float), stream);
  hipMemsetAsync(out, 0, (size_t)out_size * sizeof(float), stream);

  // 1) q_a = hs @ q_a_w^T  (split-4, atomic)
  gemv2_k<kH, 4, true><<<dim3(kQLR / 8, 4), 256, 0, stream>>>(qaw, hs, qa, kQLR);
  // 2) rmsnorm
  rmsnorm_k<<<B, 256, 0, stream>>>(qa, qlnw, qan);
  // 3) q = q_a_n @ q_b_w^T
  gemv2_k<kQLR, 1, false><<<dim3((kNH * kDQ) / 8, 1), 256, 0, stream>>>(qbw, qan, q, kNH * kDQ);
  // 4) q absorption (d-split, atomic)
  qabs_k<<<dim3(kNH, 4), 256, 0, stream>>>(q, kvbw, qabs);
  // 5) fused rope + scores + split-softmax + PV partials
  attn_k<<<dim3(KV / 64, 8, B), 256, 0, stream>>>(qabs, q, ckv, kpe, ctxp, ml, KV);
  // 6) weighted fold + v projection
  vproj_k<<<dim3(kNH, 4), 256, 0, stream>>>(ctxp, ml, kvbw, oh);
  // 7) out = oh @ o_w^T  (split-4, atomic into d_out)
  gemv2_k<kNH * kDV, 4, true><<<dim3(kH / 8, 4), 256, 0, stream>>>(ow, oh, out, kH);
}

// Round 3
// 659.822 us; speedup vs baseline: 1.0147x; 1.0033x over previous
//
#include <hip/hip_runtime.h>
#include <math.h>

// Problem constants (DeepseekV2 MLA decode)
constexpr int kH    = 5120;
constexpr int kQLR  = 1536;
constexpr int kNH   = 128;
constexpr int kDQ   = 192;
constexpr int kDN   = 128;
constexpr int kDR   = 64;
constexpr int kKVLR = 512;
constexpr int kDV   = 128;

// ---------------------------------------------------------------------------
// 2-batch GEMV, 2 rows per wave, split-K over blockIdx.y.
// y[b,row] = sum_i W[row,i]*x[b,i].  ATOMIC=true -> atomicAdd partials.
// grid (R/8, SPLIT), block 256.
// ---------------------------------------------------------------------------
template<int IN, int SPLIT, bool ATOMIC>
__global__ __launch_bounds__(256) void gemv2_k(const float* __restrict__ W,
                                               const float* __restrict__ x,
                                               float* __restrict__ y, int R) {
  constexpr int CH = IN / SPLIT;
  constexpr int F4 = CH / 256;  // float4 per lane per row-chunk
  int lane = threadIdx.x & 63, wave = threadIdx.x >> 6;
  int r0 = blockIdx.x * 8 + wave * 2;
  int c0 = blockIdx.y * CH;
  const float4* W0 = (const float4*)(W + (size_t)r0 * IN + c0);
  const float4* W1 = (const float4*)(W + (size_t)(r0 + 1) * IN + c0);
  const float4* x0 = (const float4*)(x + c0);
  const float4* x1 = (const float4*)(x + IN + c0);
  float a00 = 0.f, a01 = 0.f, a10 = 0.f, a11 = 0.f;
#pragma unroll 4
  for (int i = 0; i < F4; ++i) {
    int idx = lane + (i << 6);
    float4 w0 = W0[idx];
    float4 w1 = W1[idx];
    float4 u = x0[idx];
    float4 v = x1[idx];
    a00 = fmaf(w0.x,u.x,fmaf(w0.y,u.y,fmaf(w0.z,u.z,fmaf(w0.w,u.w,a00))));
    a01 = fmaf(w0.x,v.x,fmaf(w0.y,v.y,fmaf(w0.z,v.z,fmaf(w0.w,v.w,a01))));
    a10 = fmaf(w1.x,u.x,fmaf(w1.y,u.y,fmaf(w1.z,u.z,fmaf(w1.w,u.w,a10))));
    a11 = fmaf(w1.x,v.x,fmaf(w1.y,v.y,fmaf(w1.z,v.z,fmaf(w1.w,v.w,a11))));
  }
#pragma unroll
  for (int off = 32; off > 0; off >>= 1) {
    a00 += __shfl_down(a00, off, 64);
    a01 += __shfl_down(a01, off, 64);
    a10 += __shfl_down(a10, off, 64);
    a11 += __shfl_down(a11, off, 64);
  }
  if (lane == 0) {
    if (ATOMIC) {
      atomicAdd(&y[r0], a00);
      atomicAdd(&y[(size_t)R + r0], a01);
      atomicAdd(&y[r0 + 1], a10);
      atomicAdd(&y[(size_t)R + r0 + 1], a11);
    } else {
      y[r0] = a00;
      y[(size_t)R + r0] = a01;
      y[r0 + 1] = a10;
      y[(size_t)R + r0 + 1] = a11;
    }
  }
}

// ---------------------------------------------------------------------------
// RMSNorm over QLR=1536 per batch
// ---------------------------------------------------------------------------
__global__ __launch_bounds__(256) void rmsnorm_k(const float* __restrict__ qa,
                                                 const float* __restrict__ w,
                                                 float* __restrict__ out) {
  int b = blockIdx.x, t = threadIdx.x;
  const float* x = qa + (size_t)b * kQLR;
  float s = 0.f;
  for (int i = t; i < kQLR; i += 256) { float v = x[i]; s = fmaf(v, v, s); }
  __shared__ float red[4];
#pragma unroll
  for (int off = 32; off > 0; off >>= 1) s += __shfl_down(s, off, 64);
  if ((t & 63) == 0) red[t >> 6] = s;
  __syncthreads();
  float tot = red[0] + red[1] + red[2] + red[3];
  float scale = rsqrtf(tot / (float)kQLR + 1e-6f);
  for (int i = t; i < kQLR; i += 256) out[(size_t)b * kQLR + i] = x[i] * scale * w[i];
}

// ---------------------------------------------------------------------------
// q absorption, atomic-free:
// qabs[b,h,c] = sum_d q_nope[b,h,d] * kv_b_w[h*256+d, c]
// grid (NH, 2 column-halves), block 128.
// thread t owns float2 column ch*128+t (256 floats per block, exact).
// ---------------------------------------------------------------------------
__global__ __launch_bounds__(128) void qabs2_k(const float* __restrict__ q,
                                               const float* __restrict__ kvw,
                                               float* __restrict__ qabs) {
  int h = blockIdx.x, ch = blockIdx.y;
  int t = threadIdx.x;
  __shared__ float qn[2][128];
  for (int i = t; i < 256; i += 128) {
    int b = i >> 7, d = i & 127;
    qn[b][d] = q[((size_t)b * kNH + h) * kDQ + d];
  }
  __syncthreads();
  float a0x = 0.f, a0y = 0.f, a1x = 0.f, a1y = 0.f;
  const float2* wb = (const float2*)(kvw + (size_t)h * 256 * kKVLR) + ch * 128 + t;
#pragma unroll 8
  for (int d = 0; d < 128; ++d) {
    float2 w = wb[(size_t)d * (kKVLR / 2)];
    float q0 = qn[0][d], q1 = qn[1][d];
    a0x = fmaf(q0, w.x, a0x); a0y = fmaf(q0, w.y, a0y);
    a1x = fmaf(q1, w.x, a1x); a1y = fmaf(q1, w.y, a1y);
  }
  float2* p0 = (float2*)(qabs + (size_t)h * kKVLR) + ch * 128 + t;
  float2* p1 = (float2*)(qabs + ((size_t)kNH + h) * kKVLR) + ch * 128 + t;
  *p0 = make_float2(a0x, a0y);
  *p1 = make_float2(a1x, a1y);
}

// ---------------------------------------------------------------------------
// Fused flash attention over a 64-kv split:
//   - rope(k_pe) fused into LDS staging; rope(q_pe) into LDS tile
//   - scores = (qabs.c + q_pe_rot.k_pe_rot)/sqrt(192)
//   - per-split softmax partial: m=max, p=exp(s-m), l=sum(p)
//   - ctx partial: ctxp[ks,b,h,:] = sum_k p*c   (unnormalized)
//   - (m,l) stored to ml for the weighted fold in fold_k
// grid (KV/64, 8 head-groups-of-16, B), block 256; wave handles 4 heads in QK.
// ---------------------------------------------------------------------------
__global__ __launch_bounds__(256) void attn_k(const float* __restrict__ qabs,
                                              const float* __restrict__ qfull,
                                              const float* __restrict__ c,
                                              const float* __restrict__ kpe,
                                              float* __restrict__ ctxp,
                                              float* __restrict__ ml, int KV) {
  int ks = blockIdx.x, hg = blockIdx.y, b = blockIdx.z;
  int t = threadIdx.x, lane = t & 63, wave = t >> 6;
  int h0 = __builtin_amdgcn_readfirstlane(hg * 16 + wave * 4);
  int k0 = ks * 64;
  __shared__ float cl[64 * 129];   // c chunk [64][128] (+1 pad)
  __shared__ float kl[64 * 65];    // rotated k_pe [64][64] (+1 pad)
  __shared__ float ql[16 * 64];    // rotated q_pe for 16 heads
  __shared__ float al[64 * 20];    // p values [k][head-in-group]

  constexpr float kNegLog = -0.28782313662425572f;  // -ln(10000)/32

  // stage + rotate k_pe chunk [64][64]
  {
    const float4* src = (const float4*)(kpe + ((size_t)b * KV + k0) * kDR);
#pragma unroll
    for (int i = 0; i < 4; ++i) {
      int idx = t + i * 256;
      int r = idx >> 4, c4 = idx & 15;
      float4 v = src[r * 16 + c4];
      float fk = (float)(k0 + r);
      float inv0 = expf(kNegLog * (float)(c4 * 2));
      float inv1 = expf(kNegLog * (float)(c4 * 2 + 1));
      float s0, c0, s1, c1;
      sincosf(fk * inv0, &s0, &c0);
      sincosf(fk * inv1, &s1, &c1);
      float* d = &kl[r * 65 + (c4 << 2)];
      d[0] = v.x * c0 - v.y * s0;
      d[1] = v.x * s0 + v.y * c0;
      d[2] = v.z * c1 - v.w * s1;
      d[3] = v.z * s1 + v.w * c1;
    }
  }
  // rotate q_pe for this head group into ql (pos = KV-1)
  {
    float fp = (float)(KV - 1);
    for (int pi = t; pi < 512; pi += 256) {
      int j = pi >> 5, i = pi & 31;
      float inv = expf(kNegLog * (float)i);
      float s, cc;
      sincosf(fp * inv, &s, &cc);
      const float* qp = qfull + ((size_t)b * kNH + hg * 16 + j) * kDQ + kDN + 2 * i;
      float x0 = qp[0], x1 = qp[1];
      ql[j * 64 + 2 * i]     = x0 * cc - x1 * s;
      ql[j * 64 + 2 * i + 1] = x0 * s + x1 * cc;
    }
  }

  float acc[4] = {0.f, 0.f, 0.f, 0.f};
  for (int cch = 0; cch < 4; ++cch) {
    __syncthreads();
    const float* cb = c + ((size_t)b * KV + k0) * kKVLR + cch * 128;
#pragma unroll
    for (int i = 0; i < 8; ++i) {
      int idx = t + i * 256;
      int r = idx >> 5, c4 = idx & 31;
      float4 v = *(const float4*)(cb + (size_t)r * kKVLR + (c4 << 2));
      float* d = &cl[r * 129 + (c4 << 2)];
      d[0] = v.x; d[1] = v.y; d[2] = v.z; d[3] = v.w;
    }
    __syncthreads();
    const float* qb = qabs + ((size_t)b * kNH + h0) * kKVLR + cch * 128;
#pragma unroll 4
    for (int cc2 = 0; cc2 < 128; ++cc2) {
      float cv = cl[lane * 129 + cc2];
#pragma unroll
      for (int j = 0; j < 4; ++j)
        acc[j] = fmaf(cv, qb[(size_t)j * kKVLR + cc2], acc[j]);
    }
  }
  // pe contribution (kl rows x ql broadcast)
  {
#pragma unroll 4
    for (int i = 0; i < 64; ++i) {
      float kv = kl[lane * 65 + i];
#pragma unroll
      for (int j = 0; j < 4; ++j)
        acc[j] = fmaf(kv, ql[(wave * 4 + j) * 64 + i], acc[j]);
    }
  }

  // per-head softmax partial over this split's 64 kv (cross-lane)
  const float scale = 1.0f / sqrtf(192.0f);
  float pj[4], mj[4], lj[4];
#pragma unroll
  for (int j = 0; j < 4; ++j) {
    float s = acc[j] * scale;
    float m = s;
#pragma unroll
    for (int off = 32; off > 0; off >>= 1) m = fmaxf(m, __shfl_xor(m, off, 64));
    float p = __expf(s - m);
    float l = p;
#pragma unroll
    for (int off = 32; off > 0; off >>= 1) l += __shfl_xor(l, off, 64);
    pj[j] = p; mj[j] = m; lj[j] = l;
  }
  *(float4*)&al[lane * 20 + wave * 4] = make_float4(pj[0], pj[1], pj[2], pj[3]);
  if (lane == 0) {
#pragma unroll
    for (int j = 0; j < 4; ++j) {
      float2* mp = (float2*)(ml + (((size_t)b * kNH + h0 + j) * 32 + ks) * 2);
      *mp = make_float2(mj[j], lj[j]);
    }
  }
  __syncthreads();

  // PV partial (unnormalized): thread -> float2 column of 512
  float2 accv[16];
#pragma unroll
  for (int j = 0; j < 16; ++j) accv[j] = make_float2(0.f, 0.f);
  const float2* c2 = (const float2*)(c + ((size_t)b * KV + k0) * kKVLR);
#pragma unroll 2
  for (int k = 0; k < 64; ++k) {
    float2 cv = c2[k * (kKVLR / 2) + t];
#pragma unroll
    for (int j4 = 0; j4 < 4; ++j4) {
      float4 av = *(const float4*)&al[k * 20 + j4 * 4];
      accv[j4*4+0].x = fmaf(av.x, cv.x, accv[j4*4+0].x);
      accv[j4*4+0].y = fmaf(av.x, cv.y, accv[j4*4+0].y);
      accv[j4*4+1].x = fmaf(av.y, cv.x, accv[j4*4+1].x);
      accv[j4*4+1].y = fmaf(av.y, cv.y, accv[j4*4+1].y);
      accv[j4*4+2].x = fmaf(av.z, cv.x, accv[j4*4+2].x);
      accv[j4*4+2].y = fmaf(av.z, cv.y, accv[j4*4+2].y);
      accv[j4*4+3].x = fmaf(av.w, cv.x, accv[j4*4+3].x);
      accv[j4*4+3].y = fmaf(av.w, cv.y, accv[j4*4+3].y);
    }
  }
#pragma unroll
  for (int j = 0; j < 16; ++j) {
    float2* dst = (float2*)(ctxp + (((size_t)ks * 2 + b) * kNH + hg * 16 + j) * kKVLR);
    dst[t] = accv[j];
  }
}

// ---------------------------------------------------------------------------
// weighted fold of 32 flash partials (read ctxp ONCE):
//   M = max_s m_s ; w_s = exp(m_s - M) ; L = sum w_s*l_s
//   ctx[b,h,:] = sum_s w_s * ctxp_s ; invl[b,h] = 1/L
// grid (NH, B), block 256 (thread -> float2 column).
// ---------------------------------------------------------------------------
__global__ __launch_bounds__(256) void fold_k(const float* __restrict__ ctxp,
                                              const float* __restrict__ ml,
                                              float* __restrict__ ctx,
                                              float* __restrict__ invl) {
  int h = blockIdx.x, b = blockIdx.y;
  int t = threadIdx.x;
  const float2* mlb = (const float2*)(ml + ((size_t)b * kNH + h) * 64);
  float M = -1e30f;
#pragma unroll 8
  for (int s = 0; s < 32; ++s) M = fmaxf(M, mlb[s].x);
  float L = 0.f;
  float2 acc = make_float2(0.f, 0.f);
#pragma unroll 4
  for (int s = 0; s < 32; ++s) {
    float2 e = mlb[s];
    float w = __expf(e.x - M);
    L = fmaf(w, e.y, L);
    float2 v = ((const float2*)(ctxp + (((size_t)s * 2 + b) * kNH + h) * kKVLR))[t];
    acc.x = fmaf(w, v.x, acc.x);
    acc.y = fmaf(w, v.y, acc.y);
  }
  ((float2*)(ctx + ((size_t)b * kNH + h) * kKVLR))[t] = acc;
  if (t == 0) invl[(size_t)b * kNH + h] = 1.0f / L;
}

// ---------------------------------------------------------------------------
// v-projection from folded ctx: oh[b,h,d] = (W_v[h][d,:] . ctx[b,h,:]) * invl
// grid (NH, 4 d-quarters), block 256.
// ---------------------------------------------------------------------------
__global__ __launch_bounds__(256) void vproj_k(const float* __restrict__ ctx,
                                               const float* __restrict__ invl,
                                               const float* __restrict__ kvw,
                                               float* __restrict__ oh) {
  int h = blockIdx.x, dq = blockIdx.y;
  int t = threadIdx.x, lane = t & 63, wave = t >> 6;
  // lane -> 8 consecutive ctx cols (two float4 loads), both batches
  const float4* c0 = (const float4*)(ctx + (size_t)h * kKVLR) + lane * 2;
  const float4* c1 = (const float4*)(ctx + ((size_t)kNH + h) * kKVLR) + lane * 2;
  float4 ca = c0[0], cb = c0[1];
  float4 da = c1[0], db = c1[1];
  float inv0 = invl[h];
  float inv1 = invl[kNH + h];
#pragma unroll
  for (int i = 0; i < 8; ++i) {
    int d = dq * 32 + wave * 8 + i;
    const float4* w4 = (const float4*)(kvw + ((size_t)h * 256 + 128 + d) * kKVLR) + lane * 2;
    float4 wa = w4[0], wb = w4[1];
    float s0 = wa.x * ca.x + wa.y * ca.y + wa.z * ca.z + wa.w * ca.w
             + wb.x * cb.x + wb.y * cb.y + wb.z * cb.z + wb.w * cb.w;
    float s1 = wa.x * da.x + wa.y * da.y + wa.z * da.z + wa.w * da.w
             + wb.x * db.x + wb.y * db.y + wb.z * db.z + wb.w * db.w;
#pragma unroll
    for (int off = 32; off > 0; off >>= 1) {
      s0 += __shfl_down(s0, off, 64);
      s1 += __shfl_down(s1, off, 64);
    }
    if (lane == 0) {
      oh[(size_t)h * kDV + d] = s0 * inv0;
      oh[((size_t)kNH + h) * kDV + d] = s1 * inv1;
    }
  }
}

// ---------------------------------------------------------------------------
extern "C" void kernel_launch(void* const* d_in, const int* in_sizes, int n_in,
                              void* d_out, int out_size, void* d_ws, size_t ws_size,
                              hipStream_t stream) {
  const float* hs   = (const float*)d_in[0];
  const float* ckv  = (const float*)d_in[1];
  const float* kpe  = (const float*)d_in[2];
  const float* qaw  = (const float*)d_in[3];
  const float* qlnw = (const float*)d_in[4];
  const float* qbw  = (const float*)d_in[5];
  const float* kvbw = (const float*)d_in[6];
  const float* ow   = (const float*)d_in[7];
  float* out = (float*)d_out;

  int B  = in_sizes[0] / kH;              // 2
  int KV = in_sizes[2] / (B * kDR);       // 2048

  float* ws   = (float*)d_ws;
  float* qa   = ws;                                    // B*QLR (memset)
  float* qan  = qa + (size_t)B * kQLR;                 // B*QLR
  float* q    = qan + (size_t)B * kQLR;                // B*NH*DQ
  float* qabs = q + (size_t)B * kNH * kDQ;             // B*NH*KVLR
  float* ctxp = qabs + (size_t)B * kNH * kKVLR;        // 32*B*NH*KVLR
  float* ml   = ctxp + (size_t)32 * B * kNH * kKVLR;   // B*NH*32*2 (m,l)
  float* ctx  = ml + (size_t)B * kNH * 64;             // B*NH*KVLR
  float* invl = ctx + (size_t)B * kNH * kKVLR;         // B*NH
  float* oh   = invl + (size_t)B * kNH;                // B*NH*DV

  // zero atomic-accumulation targets
  hipMemsetAsync(qa, 0, (size_t)B * kQLR * sizeof(float), stream);
  hipMemsetAsync(out, 0, (size_t)out_size * sizeof(float), stream);

  // 1) q_a = hs @ q_a_w^T  (split-4, atomic)
  gemv2_k<kH, 4, true><<<dim3(kQLR / 8, 4), 256, 0, stream>>>(qaw, hs, qa, kQLR);
  // 2) rmsnorm
  rmsnorm_k<<<B, 256, 0, stream>>>(qa, qlnw, qan);
  // 3) q = q_a_n @ q_b_w^T
  gemv2_k<kQLR, 1, false><<<dim3((kNH * kDQ) / 8, 1), 256, 0, stream>>>(qbw, qan, q, kNH * kDQ);
  // 4) q absorption (atomic-free, column-split)
  qabs2_k<<<dim3(kNH, 2), 128, 0, stream>>>(q, kvbw, qabs);
  // 5) fused rope + scores + split-softmax + PV partials
  attn_k<<<dim3(KV / 64, 8, B), 256, 0, stream>>>(qabs, q, ckv, kpe, ctxp, ml, KV);
  // 6) weighted fold of partials (ctxp read once)
  fold_k<<<dim3(kNH, B), 256, 0, stream>>>(ctxp, ml, ctx, invl);
  // 7) v projection
  vproj_k<<<dim3(kNH, 4), 256, 0, stream>>>(ctx, invl, kvbw, oh);
  // 8) out = oh @ o_w^T  (split-4, atomic into d_out)
  gemv2_k<kNH * kDV, 4, true><<<dim3(kH / 8, 4), 256, 0, stream>>>(ow, oh, out, kH);
}